// Round 3
// baseline (617.799 us; speedup 1.0000x reference)
//
#include <hip/hip_runtime.h>

typedef __bf16 bf16;
typedef unsigned short u16;
typedef __attribute__((ext_vector_type(8))) __bf16 bf16x8;
typedef __attribute__((ext_vector_type(4))) float f32x4;
typedef const __attribute__((address_space(1))) char gchar;
typedef const __attribute__((address_space(1))) bf16x8 gbf16x8;

#define N_PTS 400000
#define KVOL 27
#define SCHED0() __builtin_amdgcn_sched_barrier(0)

__device__ __forceinline__ f32x4 mfma16(bf16x8 a, bf16x8 b, f32x4 c) {
  return __builtin_amdgcn_mfma_f32_16x16x32_bf16(a, b, c, 0, 0, 0);
}

// ---------------- cast feats fp32 -> bf16 (vectorized 8/thread) ----------------
__global__ __launch_bounds__(256) void cast_feats_k(const float4* __restrict__ in,
                                                    bf16x8* __restrict__ out) {
  int i = blockIdx.x * 256 + threadIdx.x;   // 6,400,000 threads exactly
  float4 a = in[2 * i], b = in[2 * i + 1];
  bf16x8 v;
  v[0] = (bf16)a.x; v[1] = (bf16)a.y; v[2] = (bf16)a.z; v[3] = (bf16)a.w;
  v[4] = (bf16)b.x; v[5] = (bf16)b.y; v[6] = (bf16)b.z; v[7] = (bf16)b.w;
  out[i] = v;
}

// ---- pack weights into per-lane MFMA B-fragment streams ----
// Wt2[k][kf][ct][lane][8]: value j = conv_w[k][ci][co], ci=kf*32+(lane>>4)*8+j,
// co=ct*16+(lane&15).  lt2[kf][ct][lane][8] likewise from lin_w[co][ci].  + zrow.
__global__ __launch_bounds__(256) void cast_w_k(const float* __restrict__ conv_w,
                                                const float* __restrict__ lin_w,
                                                bf16x8* __restrict__ wt2,
                                                bf16x8* __restrict__ lt2,
                                                bf16x8* __restrict__ zrow) {
  int t = blockIdx.x * 256 + threadIdx.x;   // 57600 threads, 57360 used
  if (t < KVOL * 4 * 8 * 64) {
    int lane = t & 63;
    int ct = (t >> 6) & 7;
    int kf = (t >> 9) & 3;
    int k = t >> 11;
    int co = ct * 16 + (lane & 15);
    int ci0 = kf * 32 + ((lane >> 4) & 3) * 8;
    bf16x8 v;
#pragma unroll
    for (int j = 0; j < 8; ++j)
      v[j] = (bf16)conv_w[(k * 128 + ci0 + j) * 128 + co];
    wt2[t] = v;
  } else if (t < KVOL * 4 * 8 * 64 + 2048) {
    int t2 = t - KVOL * 4 * 8 * 64;
    int lane = t2 & 63;
    int ct = (t2 >> 6) & 7;
    int kf = t2 >> 9;
    int co = ct * 16 + (lane & 15);
    int ci0 = kf * 32 + ((lane >> 4) & 3) * 8;
    bf16x8 v;
#pragma unroll
    for (int j = 0; j < 8; ++j) v[j] = (bf16)lin_w[co * 128 + ci0 + j];
    lt2[t2] = v;
  } else if (t < KVOL * 4 * 8 * 64 + 2048 + 16) {
    bf16x8 v = {};
    zrow[t - (KVOL * 4 * 8 * 64 + 2048)] = v;
  }
}

// ---------------- fused conv (barrier-free) + linear + layernorm ----------------
__global__ __launch_bounds__(256, 2) void fused_k(
    const bf16* __restrict__ featsb,
    const int* __restrict__ nbr,
    const bf16* __restrict__ wt2,     // [27][4][8][64][8] B-frag stream
    const bf16* __restrict__ lt2,     // [4][8][64][8] B-frag stream
    const bf16* __restrict__ zrow,    // 128 zeros
    const float* __restrict__ conv_b,
    const float* __restrict__ lin_b,
    const float* __restrict__ ln_g,
    const float* __restrict__ ln_b,
    float* __restrict__ out) {
  __shared__ __align__(16) u16 cobuf[256 * 128];   // 64 KB conv-out (swizzled)

  const int tid = threadIdx.x;
  const int lane = tid & 63;
  const int wv = tid >> 6;
  const int l15 = lane & 15;
  const int l4 = lane >> 4;
  const int lp = lane & 7;

  // bijective XCD-aware swizzle (m204)
  const int nwg = gridDim.x;
  const int bid0 = blockIdx.x;
  const int q = nwg >> 3, r8 = nwg & 7;
  const int xcd = bid0 & 7, lo = bid0 >> 3;
  const int bid = (xcd < r8 ? xcd * (q + 1) : r8 * (q + 1) + (xcd - r8) * q) + lo;

  const int row0 = bid * 256;
  const int rb = row0 + wv * 64 + l15;  // + rg*16 -> this lane's rows
  const int aoff = l4 * 16;             // byte offset of A-frag slice in a row

  // ---- prologue: idx(0),(1); gather A(0) ----
  int idx_nxt[4];
  int idx_t0[4];
#pragma unroll
  for (int rg = 0; rg < 4; ++rg) {
    int r = rb + rg * 16;
    int rr = r < N_PTS ? r : N_PTS - 1;
    int v0 = nbr[(size_t)rr * KVOL + 0];
    int v1 = nbr[(size_t)rr * KVOL + 1];
    idx_t0[rg] = r < N_PTS ? v0 : -1;
    idx_nxt[rg] = r < N_PTS ? v1 : -1;
  }
  bf16x8 a[4][4];
#pragma unroll
  for (int rg = 0; rg < 4; ++rg) {
    gchar* base = (idx_t0[rg] < 0) ? (gchar*)zrow
                                   : (gchar*)featsb + (size_t)idx_t0[rg] * 256;
    base += aoff;
#pragma unroll
    for (int kf = 0; kf < 4; ++kf) a[rg][kf] = *(gbf16x8*)(base + kf * 64);
  }
  f32x4 acc[4][8];
#pragma unroll
  for (int rg = 0; rg < 4; ++rg)
#pragma unroll
    for (int ct = 0; ct < 8; ++ct) acc[rg][ct] = (f32x4)0.f;

  // ---- main loop: no barriers, no LDS; B direct from L2 ----
  for (int t = 0; t < KVOL; ++t) {
    gchar* nb[4];
#pragma unroll
    for (int rg = 0; rg < 4; ++rg) {
      gchar* base = (idx_nxt[rg] < 0) ? (gchar*)zrow
                                      : (gchar*)featsb + (size_t)idx_nxt[rg] * 256;
      nb[rg] = base + aoff;
    }
    {
      int k2 = t + 2 < KVOL ? t + 2 : KVOL - 1;
#pragma unroll
      for (int rg = 0; rg < 4; ++rg) {
        int r = rb + rg * 16;
        int rr = r < N_PTS ? r : N_PTS - 1;
        int v = nbr[(size_t)rr * KVOL + k2];
        idx_nxt[rg] = r < N_PTS ? v : -1;
      }
    }
    gchar* wb = (gchar*)wt2 + (size_t)t * 32768 + (size_t)lane * 16;
#pragma unroll
    for (int kf = 0; kf < 4; ++kf) {
      bf16x8 b[8];
#pragma unroll
      for (int ct = 0; ct < 8; ++ct)
        b[ct] = *(gbf16x8*)(wb + kf * 8192 + ct * 1024);
      __builtin_amdgcn_s_setprio(1);
#pragma unroll
      for (int ct = 0; ct < 8; ++ct)
#pragma unroll
        for (int rg = 0; rg < 4; ++rg)
          acc[rg][ct] = mfma16(a[rg][kf], b[ct], acc[rg][ct]);
      __builtin_amdgcn_s_setprio(0);
      // prefetch next tap's A into the slots just consumed
#pragma unroll
      for (int rg = 0; rg < 4; ++rg) a[rg][kf] = *(gbf16x8*)(nb[rg] + kf * 64);
    }
  }

  // ---- conv bias + cast bf16 -> cobuf (swizzled; intra-wave rows only) ----
  float cb[8];
#pragma unroll
  for (int ct = 0; ct < 8; ++ct) cb[ct] = conv_b[ct * 16 + l15];
#pragma unroll
  for (int rg = 0; rg < 4; ++rg) {
#pragma unroll
    for (int ct = 0; ct < 8; ++ct) {
#pragma unroll
      for (int j = 0; j < 4; ++j) {
        int rl = wv * 64 + rg * 16 + l4 * 4 + j;   // C/D layout: row = l4*4 + reg
        int c = ct * 16 + l15;
        float x = acc[rg][ct][j] + cb[ct];
        int chunk = (c >> 3) ^ (rl & 7);
        cobuf[rl * 128 + chunk * 8 + (c & 7)] = __builtin_bit_cast(u16, (bf16)x);
      }
    }
  }
  __syncthreads();   // single drain; cobuf ready (also orders the stray prefetches)

  // ---- linear layer: A from cobuf (LDS), B-frags from lt2 (L2) ----
  f32x4 acc2[4][8];
#pragma unroll
  for (int rg = 0; rg < 4; ++rg)
#pragma unroll
    for (int ct = 0; ct < 8; ++ct) acc2[rg][ct] = (f32x4)0.f;
#pragma unroll
  for (int kf = 0; kf < 4; ++kf) {
    const int chunk = (kf * 4 + l4) ^ lp;
    bf16x8 av[4];
#pragma unroll
    for (int rg = 0; rg < 4; ++rg)
      av[rg] = *(const bf16x8*)(cobuf + (wv * 64 + rg * 16 + l15) * 128 + chunk * 8);
#pragma unroll
    for (int ct = 0; ct < 8; ++ct) {
      bf16x8 b = *(gbf16x8*)((gchar*)lt2 + (kf * 8 + ct) * 1024 + lane * 16);
#pragma unroll
      for (int rg = 0; rg < 4; ++rg)
        acc2[rg][ct] = mfma16(av[rg], b, acc2[rg][ct]);
    }
  }

  // ---- + lin_b, LayerNorm (shfl reduce over 16-lane groups), guarded store ----
  float lb[8], lg[8], lbv[8];
#pragma unroll
  for (int ct = 0; ct < 8; ++ct) {
    int c = ct * 16 + l15;
    lb[ct] = lin_b[c]; lg[ct] = ln_g[c]; lbv[ct] = ln_b[c];
  }
#pragma unroll
  for (int rg = 0; rg < 4; ++rg) {
#pragma unroll
    for (int j = 0; j < 4; ++j) {
      float s = 0.f, qq = 0.f;
#pragma unroll
      for (int ct = 0; ct < 8; ++ct) {
        float x = acc2[rg][ct][j] + lb[ct];
        s += x; qq += x * x;
      }
#pragma unroll
      for (int m = 1; m <= 8; m <<= 1) {
        s += __shfl_xor(s, m, 64);
        qq += __shfl_xor(qq, m, 64);
      }
      float mu = s * (1.f / 128.f);
      float var = qq * (1.f / 128.f) - mu * mu;
      float rstd = rsqrtf(var + 1e-5f);
      int r = row0 + wv * 64 + rg * 16 + l4 * 4 + j;
      if (r < N_PTS) {
#pragma unroll
        for (int ct = 0; ct < 8; ++ct) {
          float x = acc2[rg][ct][j] + lb[ct];
          out[(size_t)r * 128 + ct * 16 + l15] = (x - mu) * rstd * lg[ct] + lbv[ct];
        }
      }
    }
  }
}

extern "C" void kernel_launch(void* const* d_in, const int* in_sizes, int n_in,
                              void* d_out, int out_size, void* d_ws, size_t ws_size,
                              hipStream_t stream) {
  const float* feats  = (const float*)d_in[0];
  const int*   nbr    = (const int*)d_in[1];
  const float* conv_w = (const float*)d_in[2];
  const float* conv_b = (const float*)d_in[3];
  const float* lin_w  = (const float*)d_in[4];
  const float* lin_b  = (const float*)d_in[5];
  const float* ln_g   = (const float*)d_in[6];
  const float* ln_b   = (const float*)d_in[7];
  float* out = (float*)d_out;

  bf16* featsb = (bf16*)d_ws;                       // 102,400,000 B
  bf16* wt2 = featsb + (size_t)N_PTS * 128;         // 884,736 B (frag stream)
  bf16* lt2 = wt2 + (size_t)KVOL * 128 * 128;       // 32,768 B
  bf16* zrow = lt2 + (size_t)128 * 128;             // 256 B zeros

  cast_feats_k<<<25000, 256, 0, stream>>>((const float4*)feats, (bf16x8*)featsb);
  cast_w_k<<<225, 256, 0, stream>>>(conv_w, lin_w, (bf16x8*)wt2, (bf16x8*)lt2, (bf16x8*)zrow);
  fused_k<<<1563, 256, 0, stream>>>(featsb, nbr, wt2, lt2, zrow,
                                    conv_b, lin_b, ln_g, ln_b, out);
}

// Round 6
// 424.825 us; speedup vs baseline: 1.4542x; 1.4542x over previous
//
#include <hip/hip_runtime.h>

typedef __bf16 bf16;
typedef unsigned short u16;
typedef __attribute__((ext_vector_type(8))) __bf16 bf16x8;
typedef __attribute__((ext_vector_type(4))) float f32x4;
typedef const __attribute__((address_space(1))) char gchar;
typedef const __attribute__((address_space(1))) bf16x8 gbf16x8;

#define N_PTS 400000
#define KVOL 27
#define SCHED0() __builtin_amdgcn_sched_barrier(0)

__device__ __forceinline__ f32x4 mfma16(bf16x8 a, bf16x8 b, f32x4 c) {
  return __builtin_amdgcn_mfma_f32_16x16x32_bf16(a, b, c, 0, 0, 0);
}

// ---------------- cast feats fp32 -> bf16 (vectorized 8/thread) ----------------
__global__ __launch_bounds__(256) void cast_feats_k(const float4* __restrict__ in,
                                                    bf16x8* __restrict__ out) {
  int i = blockIdx.x * 256 + threadIdx.x;   // 6,400,000 threads exactly
  float4 a = in[2 * i], b = in[2 * i + 1];
  bf16x8 v;
  v[0] = (bf16)a.x; v[1] = (bf16)a.y; v[2] = (bf16)a.z; v[3] = (bf16)a.w;
  v[4] = (bf16)b.x; v[5] = (bf16)b.y; v[6] = (bf16)b.z; v[7] = (bf16)b.w;
  out[i] = v;
}

// ---- build W'[k] = conv_w[k] @ lin_w^T as MFMA B-frag stream, b2 = lin_w@conv_b+lin_b ----
// wt2[k][kf][ct][lane][8]: val j = W'[k][ci][co], ci=kf*32+(lane>>4)*8+j, co=ct*16+(lane&15)
__global__ __launch_bounds__(256) void cast_w2_k(const float* __restrict__ conv_w,
                                                 const float* __restrict__ lin_w,
                                                 const float* __restrict__ conv_b,
                                                 const float* __restrict__ lin_b,
                                                 bf16x8* __restrict__ wt2,
                                                 float* __restrict__ b2,
                                                 bf16x8* __restrict__ zrow) {
  int t = blockIdx.x * 256 + threadIdx.x;   // 217 blocks, 55440 threads used
  if (t < KVOL * 2048) {
    int lane = t & 63;
    int ct = (t >> 6) & 7;
    int kf = (t >> 9) & 3;
    int k = t >> 11;
    int co = ct * 16 + (lane & 15);
    int ci0 = kf * 32 + (lane >> 4) * 8;
    float s[8];
#pragma unroll
    for (int j = 0; j < 8; ++j) s[j] = 0.f;
    const float4* lw = (const float4*)(lin_w + (size_t)co * 128);
    for (int c4 = 0; c4 < 32; ++c4) {
      float4 w = lw[c4];
#pragma unroll
      for (int j = 0; j < 8; ++j) {
        float4 cv = *(const float4*)(conv_w + ((size_t)(k * 128 + ci0 + j)) * 128 + c4 * 4);
        s[j] += cv.x * w.x + cv.y * w.y + cv.z * w.z + cv.w * w.w;
      }
    }
    bf16x8 v;
#pragma unroll
    for (int j = 0; j < 8; ++j) v[j] = (bf16)s[j];
    wt2[t] = v;
  } else if (t < KVOL * 2048 + 128) {
    int co = t - KVOL * 2048;
    float s = lin_b[co];
    for (int c = 0; c < 128; ++c) s += conv_b[c] * lin_w[(size_t)co * 128 + c];
    b2[co] = s;
  } else if (t < KVOL * 2048 + 128 + 16) {
    bf16x8 v = {};
    zrow[t - (KVOL * 2048 + 128)] = v;
  }
}

// ---------------- fused gather-GEMM (54 half-tap phases, vmcnt(0) drains) + LN ----------------
// 256 thr / 128 rows per block; wave wv: rows wv*32+[0,32), ALL 128 cols.
__global__ __launch_bounds__(256, 3) void fused_k(
    const bf16* __restrict__ featsb,
    const int* __restrict__ nbr,
    const bf16* __restrict__ wt2,     // [27][4][8][64][8] B-frag stream, 16KB per half-tap
    const float* __restrict__ b2,     // fused bias [128]
    const bf16* __restrict__ zrow,    // 128 zeros
    const float* __restrict__ ln_g,
    const float* __restrict__ ln_b,
    float* __restrict__ out) {
  __shared__ __align__(16) u16 wdb[2][8192];   // 2 x 16 KB half-tap double-buffer

  const int tid = threadIdx.x;
  const int lane = tid & 63;
  const int wv = tid >> 6;
  const int l15 = lane & 15;
  const int l4 = lane >> 4;

  // bijective XCD-aware swizzle (m204)
  const int nwg = gridDim.x;
  const int bid0 = blockIdx.x;
  const int q = nwg >> 3, r8 = nwg & 7;
  const int xcd = bid0 & 7, lo = bid0 >> 3;
  const int bid = (xcd < r8 ? xcd * (q + 1) : r8 * (q + 1) + (xcd - r8) * q) + lo;

  const int row0 = bid * 128;               // 3125 * 128 = 400000 exactly
  const int rb = row0 + wv * 32 + l15;      // + rg*16 -> this lane's A rows
  const int aoff = l4 * 16;                 // byte offset of A-frag slice in a row

  f32x4 acc[2][8];
#pragma unroll
  for (int rg = 0; rg < 2; ++rg)
#pragma unroll
    for (int ct = 0; ct < 8; ++ct) acc[rg][ct] = (f32x4)0.f;

  bf16x8 a[2][4];
  int idx_nxt[2];
  gchar* nb[2];

  auto stagef = [&](int ph, int buf) {
#pragma unroll
    for (int c = 0; c < 4; ++c) {
      const char* g = (const char*)wt2 + ((size_t)ph << 14) + c * 4096 + tid * 16;
      char* l = (char*)&wdb[buf][0] + c * 4096 + wv * 1024;   // wave-uniform base; HW adds lane*16
      __builtin_amdgcn_global_load_lds(
          (const __attribute__((address_space(1))) void*)g,
          (__attribute__((address_space(3))) void*)l, 16, 0, 0);
    }
  };

  // kh = kf within the staged half; consumes a[.][kfa+kh]; prefetches next tap's A into same slot
  auto mfma_pair = [&](int buf, int kfa) {
#pragma unroll
    for (int kh = 0; kh < 2; ++kh) {
      const int kf = kfa + kh;
      const u16* bp = &wdb[buf][0] + kh * 4096 + lane * 8;
      bf16x8 bfr[8];
#pragma unroll
      for (int ct = 0; ct < 8; ++ct) bfr[ct] = *(const bf16x8*)(bp + ct * 512);
#pragma unroll
      for (int ct = 0; ct < 8; ++ct)
#pragma unroll
        for (int rg = 0; rg < 2; ++rg)
          acc[rg][ct] = mfma16(a[rg][kf], bfr[ct], acc[rg][ct]);
#pragma unroll
      for (int rg = 0; rg < 2; ++rg)
        a[rg][kf] = *(gbf16x8*)(nb[rg] + kf * 64);
    }
  };

  // ---- prologue: gather A(0); idx(1); stage half 0 ----
  {
    int idx0[2];
#pragma unroll
    for (int rg = 0; rg < 2; ++rg)
      idx0[rg] = nbr[(size_t)(rb + rg * 16) * KVOL + 0];
#pragma unroll
    for (int rg = 0; rg < 2; ++rg) {
      gchar* base = ((idx0[rg] < 0) ? (gchar*)zrow
                                    : (gchar*)featsb + (size_t)idx0[rg] * 256) + aoff;
#pragma unroll
      for (int kf = 0; kf < 4; ++kf) a[rg][kf] = *(gbf16x8*)(base + kf * 64);
    }
#pragma unroll
    for (int rg = 0; rg < 2; ++rg)
      idx_nxt[rg] = nbr[(size_t)(rb + rg * 16) * KVOL + 1];
  }
  stagef(0, 0);
  SCHED0();
  asm volatile("s_waitcnt vmcnt(0)" ::: "memory");
  SCHED0();
  __builtin_amdgcn_s_barrier();
  SCHED0();

  // ---- 27 taps x 2 half-phases; every phase ends with full drain + barrier ----
  for (int t = 0; t < KVOL; ++t) {
    // even phase: stage half 2t+1 -> wdb[1]; compute wdb[0] (kf 0,1)
    stagef(2 * t + 1, 1);
#pragma unroll
    for (int rg = 0; rg < 2; ++rg)
      nb[rg] = ((idx_nxt[rg] < 0) ? (gchar*)zrow
                                  : (gchar*)featsb + (size_t)idx_nxt[rg] * 256) + aoff;
    {
      int kk = (t + 2 < KVOL) ? t + 2 : KVOL - 1;
#pragma unroll
      for (int rg = 0; rg < 2; ++rg)
        idx_nxt[rg] = nbr[(size_t)(rb + rg * 16) * KVOL + kk];
    }
    mfma_pair(0, 0);
    SCHED0();
    asm volatile("s_waitcnt vmcnt(0)" ::: "memory");
    SCHED0();
    __builtin_amdgcn_s_barrier();
    SCHED0();

    // odd phase: stage half 2t+2 -> wdb[0] (if any); compute wdb[1] (kf 2,3)
    if (t < KVOL - 1) stagef(2 * t + 2, 0);
    mfma_pair(1, 2);
    SCHED0();
    asm volatile("s_waitcnt vmcnt(0)" ::: "memory");
    SCHED0();
    __builtin_amdgcn_s_barrier();
    SCHED0();
  }

  // ---- epilogue: + b2, LayerNorm (pure shuffle: each wave owns full 128 cols), store ----
  float bv[8], lg[8], lb[8];
#pragma unroll
  for (int ct = 0; ct < 8; ++ct) {
    int c = ct * 16 + l15;
    bv[ct] = b2[c]; lg[ct] = ln_g[c]; lb[ct] = ln_b[c];
  }
#pragma unroll
  for (int rg = 0; rg < 2; ++rg) {
#pragma unroll
    for (int j = 0; j < 4; ++j) {
      float s = 0.f, qq = 0.f;
#pragma unroll
      for (int ct = 0; ct < 8; ++ct) {
        float x = acc[rg][ct][j] + bv[ct];
        s += x; qq += x * x;
      }
#pragma unroll
      for (int m = 1; m <= 8; m <<= 1) {   // reduce across the 16-lane col group (same row)
        s += __shfl_xor(s, m, 64);
        qq += __shfl_xor(qq, m, 64);
      }
      float mu = s * (1.f / 128.f);
      float var = qq * (1.f / 128.f) - mu * mu;
      float rstd = rsqrtf(var + 1e-5f);
      int r = row0 + wv * 32 + rg * 16 + l4 * 4 + j;
#pragma unroll
      for (int ct = 0; ct < 8; ++ct) {
        float x = acc[rg][ct][j] + bv[ct];
        out[(size_t)r * 128 + ct * 16 + l15] = (x - mu) * rstd * lg[ct] + lb[ct];
      }
    }
  }
}

extern "C" void kernel_launch(void* const* d_in, const int* in_sizes, int n_in,
                              void* d_out, int out_size, void* d_ws, size_t ws_size,
                              hipStream_t stream) {
  const float* feats  = (const float*)d_in[0];
  const int*   nbr    = (const int*)d_in[1];
  const float* conv_w = (const float*)d_in[2];
  const float* conv_b = (const float*)d_in[3];
  const float* lin_w  = (const float*)d_in[4];
  const float* lin_b  = (const float*)d_in[5];
  const float* ln_g   = (const float*)d_in[6];
  const float* ln_b   = (const float*)d_in[7];
  float* out = (float*)d_out;

  bf16* featsb = (bf16*)d_ws;                       // 102,400,000 B
  bf16* wt2 = featsb + (size_t)N_PTS * 128;         // 884,736 B  (W' frag stream)
  float* b2 = (float*)(wt2 + (size_t)KVOL * 128 * 128);  // 512 B
  bf16* zrow = (bf16*)(b2 + 128);                   // 256 B zeros

  cast_feats_k<<<25000, 256, 0, stream>>>((const float4*)feats, (bf16x8*)featsb);
  cast_w2_k<<<217, 256, 0, stream>>>(conv_w, lin_w, conv_b, lin_b,
                                     (bf16x8*)wt2, b2, (bf16x8*)zrow);
  fused_k<<<3125, 256, 0, stream>>>(featsb, nbr, wt2, b2, zrow, ln_g, ln_b, out);
}

// Round 7
// 387.443 us; speedup vs baseline: 1.5946x; 1.0965x over previous
//
#include <hip/hip_runtime.h>

typedef __bf16 bf16;
typedef unsigned short u16;
typedef __attribute__((ext_vector_type(8))) __bf16 bf16x8;
typedef __attribute__((ext_vector_type(4))) float f32x4;
typedef const __attribute__((address_space(1))) char gchar;
typedef const __attribute__((address_space(1))) bf16x8 gbf16x8;

#define N_PTS 400000
#define KVOL 27
#define SCHED0() __builtin_amdgcn_sched_barrier(0)

__device__ __forceinline__ f32x4 mfma16(bf16x8 a, bf16x8 b, f32x4 c) {
  return __builtin_amdgcn_mfma_f32_16x16x32_bf16(a, b, c, 0, 0, 0);
}

// ---------------- cast feats fp32 -> bf16 (vectorized 8/thread) ----------------
__global__ __launch_bounds__(256) void cast_feats_k(const float4* __restrict__ in,
                                                    bf16x8* __restrict__ out) {
  int i = blockIdx.x * 256 + threadIdx.x;   // 6,400,000 threads exactly
  float4 a = in[2 * i], b = in[2 * i + 1];
  bf16x8 v;
  v[0] = (bf16)a.x; v[1] = (bf16)a.y; v[2] = (bf16)a.z; v[3] = (bf16)a.w;
  v[4] = (bf16)b.x; v[5] = (bf16)b.y; v[6] = (bf16)b.z; v[7] = (bf16)b.w;
  out[i] = v;
}

// ---- build W'[k] = conv_w[k] @ lin_w^T as MFMA B-frag stream, b2 = lin_w@conv_b+lin_b ----
// wt2[k][kf][ct][lane][8]: val j = W'[k][ci][co], ci=kf*32+(lane>>4)*8+j, co=ct*16+(lane&15)
__global__ __launch_bounds__(256) void cast_w2_k(const float* __restrict__ conv_w,
                                                 const float* __restrict__ lin_w,
                                                 const float* __restrict__ conv_b,
                                                 const float* __restrict__ lin_b,
                                                 bf16x8* __restrict__ wt2,
                                                 float* __restrict__ b2,
                                                 bf16x8* __restrict__ zrow) {
  int t = blockIdx.x * 256 + threadIdx.x;   // 217 blocks, 55440 threads used
  if (t < KVOL * 2048) {
    int lane = t & 63;
    int ct = (t >> 6) & 7;
    int kf = (t >> 9) & 3;
    int k = t >> 11;
    int co = ct * 16 + (lane & 15);
    int ci0 = kf * 32 + (lane >> 4) * 8;
    float s[8];
#pragma unroll
    for (int j = 0; j < 8; ++j) s[j] = 0.f;
    const float4* lw = (const float4*)(lin_w + (size_t)co * 128);
    for (int c4 = 0; c4 < 32; ++c4) {
      float4 w = lw[c4];
#pragma unroll
      for (int j = 0; j < 8; ++j) {
        float4 cv = *(const float4*)(conv_w + ((size_t)(k * 128 + ci0 + j)) * 128 + c4 * 4);
        s[j] += cv.x * w.x + cv.y * w.y + cv.z * w.z + cv.w * w.w;
      }
    }
    bf16x8 v;
#pragma unroll
    for (int j = 0; j < 8; ++j) v[j] = (bf16)s[j];
    wt2[t] = v;
  } else if (t < KVOL * 2048 + 128) {
    int co = t - KVOL * 2048;
    float s = lin_b[co];
    for (int c = 0; c < 128; ++c) s += conv_b[c] * lin_w[(size_t)co * 128 + c];
    b2[co] = s;
  } else if (t < KVOL * 2048 + 128 + 16) {
    bf16x8 v = {};
    zrow[t - (KVOL * 2048 + 128)] = v;
  }
}

// ---------------- fused gather-GEMM (54 half-tap phases, counted vmcnt) + LN ----------------
// 256 thr / 128 rows per block; wave wv: rows wv*32+[0,32), ALL 128 cols.
__global__ __launch_bounds__(256, 3) void fused_k(
    const bf16* __restrict__ featsb,
    const int* __restrict__ nbr,
    const bf16* __restrict__ wt2,     // [27][4][8][64][8] B-frag stream, 16KB per half-tap
    const float* __restrict__ b2,     // fused bias [128]
    const bf16* __restrict__ zrow,    // 128 zeros
    const float* __restrict__ ln_g,
    const float* __restrict__ ln_b,
    float* __restrict__ out) {
  __shared__ __align__(16) u16 wdb[2][8192];   // 2 x 16 KB half-tap double-buffer

  const int tid = threadIdx.x;
  const int lane = tid & 63;
  const int wv = tid >> 6;
  const int l15 = lane & 15;
  const int l4 = lane >> 4;

  // bijective XCD-aware swizzle (m204)
  const int nwg = gridDim.x;
  const int bid0 = blockIdx.x;
  const int q = nwg >> 3, r8 = nwg & 7;
  const int xcd = bid0 & 7, lo = bid0 >> 3;
  const int bid = (xcd < r8 ? xcd * (q + 1) : r8 * (q + 1) + (xcd - r8) * q) + lo;

  const int row0 = bid * 128;               // 3125 * 128 = 400000 exactly
  const int rb = row0 + wv * 32 + l15;      // + rg*16 -> this lane's A rows
  const int aoff = l4 * 16;                 // byte offset of A-frag slice in a row

  f32x4 acc[2][8];
#pragma unroll
  for (int rg = 0; rg < 2; ++rg)
#pragma unroll
    for (int ct = 0; ct < 8; ++ct) acc[rg][ct] = (f32x4)0.f;

  bf16x8 a[2][4];
  int idx_nxt[2], idx_n2[2];
  gchar* nb[2];

  auto stagef = [&](int ph, int buf) {
#pragma unroll
    for (int c = 0; c < 4; ++c) {
      const char* g = (const char*)wt2 + ((size_t)ph << 14) + c * 4096 + tid * 16;
      char* l = (char*)&wdb[buf][0] + c * 4096 + wv * 1024;   // wave-uniform base; HW adds lane*16
      __builtin_amdgcn_global_load_lds(
          (const __attribute__((address_space(1))) void*)g,
          (__attribute__((address_space(3))) void*)l, 16, 0, 0);
    }
  };

  // kh = kf within the staged half; consumes a[.][kfa+kh]; prefetches next tap's A into same slot
  auto mfma_pair = [&](int buf, int kfa) {
#pragma unroll
    for (int kh = 0; kh < 2; ++kh) {
      const int kf = kfa + kh;
      const u16* bp = &wdb[buf][0] + kh * 4096 + lane * 8;
      bf16x8 bfr[8];
#pragma unroll
      for (int ct = 0; ct < 8; ++ct) bfr[ct] = *(const bf16x8*)(bp + ct * 512);
      __builtin_amdgcn_s_setprio(1);
#pragma unroll
      for (int ct = 0; ct < 8; ++ct)
#pragma unroll
        for (int rg = 0; rg < 2; ++rg)
          acc[rg][ct] = mfma16(a[rg][kf], bfr[ct], acc[rg][ct]);
      __builtin_amdgcn_s_setprio(0);
#pragma unroll
      for (int rg = 0; rg < 2; ++rg)
        a[rg][kf] = *(gbf16x8*)(nb[rg] + kf * 64);
    }
  };

  // ---- prologue: gather A(0); idx(1); stage half 0 ----
  {
    int idx0[2];
#pragma unroll
    for (int rg = 0; rg < 2; ++rg)
      idx0[rg] = nbr[(size_t)(rb + rg * 16) * KVOL + 0];
#pragma unroll
    for (int rg = 0; rg < 2; ++rg) {
      gchar* base = ((idx0[rg] < 0) ? (gchar*)zrow
                                    : (gchar*)featsb + (size_t)idx0[rg] * 256) + aoff;
#pragma unroll
      for (int kf = 0; kf < 4; ++kf) a[rg][kf] = *(gbf16x8*)(base + kf * 64);
    }
#pragma unroll
    for (int rg = 0; rg < 2; ++rg)
      idx_nxt[rg] = nbr[(size_t)(rb + rg * 16) * KVOL + 1];
  }
  stagef(0, 0);
  SCHED0();
  asm volatile("s_waitcnt vmcnt(0)" ::: "memory");
  SCHED0();
  __builtin_amdgcn_s_barrier();
  SCHED0();

  // ---- 27 taps x 2 half-phases; counted end-of-phase waits, issue-order pinned ----
  for (int t = 0; t < KVOL; ++t) {
    // EVEN phase: stage half 2t+1 -> wdb[1] [4 DMA]; idx(t+2) [2 loads];
    //             compute wdb[0] (kf 0,1) with 4 A-prefetch loads inside.
    stagef(2 * t + 1, 1);
    SCHED0();                                   // pin: DMAs before idx loads
    {
      int kk = (t + 2 < KVOL) ? t + 2 : KVOL - 1;
#pragma unroll
      for (int rg = 0; rg < 2; ++rg)
        idx_n2[rg] = nbr[(size_t)(rb + rg * 16) * KVOL + kk];
    }
    SCHED0();                                   // pin: idx loads before MFMA region
#pragma unroll
    for (int rg = 0; rg < 2; ++rg)
      nb[rg] = ((idx_nxt[rg] < 0) ? (gchar*)zrow
                                  : (gchar*)featsb + (size_t)idx_nxt[rg] * 256) + aoff;
    mfma_pair(0, 0);
    SCHED0();                                   // pin: A-prefetches before the wait
    // youngest 6 = 2 idx + 4 A-prefetch; everything older (incl. this phase's 4 DMA) retired
    asm volatile("s_waitcnt vmcnt(6)" ::: "memory");
    SCHED0();
    __builtin_amdgcn_s_barrier();
    SCHED0();

    // ODD phase: stage half 2t+2 -> wdb[0] [4 DMA]; compute wdb[1] (kf 2,3), 4 A-prefetch.
    if (t < KVOL - 1) stagef(2 * t + 2, 0);
    SCHED0();                                   // pin: DMAs before MFMA region
    mfma_pair(1, 2);
    SCHED0();                                   // pin: A-prefetches before the wait
    // youngest 4 = this phase's 4 A-prefetch; this phase's 4 DMA retired
    asm volatile("s_waitcnt vmcnt(4)" ::: "memory");
    SCHED0();
    __builtin_amdgcn_s_barrier();
    SCHED0();

#pragma unroll
    for (int rg = 0; rg < 2; ++rg) idx_nxt[rg] = idx_n2[rg];
  }

  // ---- final drain (stray DMA/prefetch) ----
  SCHED0();
  asm volatile("s_waitcnt vmcnt(0)" ::: "memory");
  SCHED0();

  // ---- epilogue: + b2, LayerNorm (pure shuffle: each wave owns full 128 cols), store ----
  float bv[8], lg[8], lb[8];
#pragma unroll
  for (int ct = 0; ct < 8; ++ct) {
    int c = ct * 16 + l15;
    bv[ct] = b2[c]; lg[ct] = ln_g[c]; lb[ct] = ln_b[c];
  }
#pragma unroll
  for (int rg = 0; rg < 2; ++rg) {
#pragma unroll
    for (int j = 0; j < 4; ++j) {
      float s = 0.f, qq = 0.f;
#pragma unroll
      for (int ct = 0; ct < 8; ++ct) {
        float x = acc[rg][ct][j] + bv[ct];
        s += x; qq += x * x;
      }
#pragma unroll
      for (int m = 1; m <= 8; m <<= 1) {   // reduce across the 16-lane col group (same row)
        s += __shfl_xor(s, m, 64);
        qq += __shfl_xor(qq, m, 64);
      }
      float mu = s * (1.f / 128.f);
      float var = qq * (1.f / 128.f) - mu * mu;
      float rstd = rsqrtf(var + 1e-5f);
      int r = row0 + wv * 32 + rg * 16 + l4 * 4 + j;
#pragma unroll
      for (int ct = 0; ct < 8; ++ct) {
        float x = acc[rg][ct][j] + bv[ct];
        out[(size_t)r * 128 + ct * 16 + l15] = (x - mu) * rstd * lg[ct] + lb[ct];
      }
    }
  }
}

extern "C" void kernel_launch(void* const* d_in, const int* in_sizes, int n_in,
                              void* d_out, int out_size, void* d_ws, size_t ws_size,
                              hipStream_t stream) {
  const float* feats  = (const float*)d_in[0];
  const int*   nbr    = (const int*)d_in[1];
  const float* conv_w = (const float*)d_in[2];
  const float* conv_b = (const float*)d_in[3];
  const float* lin_w  = (const float*)d_in[4];
  const float* lin_b  = (const float*)d_in[5];
  const float* ln_g   = (const float*)d_in[6];
  const float* ln_b   = (const float*)d_in[7];
  float* out = (float*)d_out;

  bf16* featsb = (bf16*)d_ws;                       // 102,400,000 B
  bf16* wt2 = featsb + (size_t)N_PTS * 128;         // 884,736 B  (W' frag stream)
  float* b2 = (float*)(wt2 + (size_t)KVOL * 128 * 128);  // 512 B
  bf16* zrow = (bf16*)(b2 + 128);                   // 256 B zeros

  cast_feats_k<<<25000, 256, 0, stream>>>((const float4*)feats, (bf16x8*)featsb);
  cast_w2_k<<<217, 256, 0, stream>>>(conv_w, lin_w, conv_b, lin_b,
                                     (bf16x8*)wt2, b2, (bf16x8*)zrow);
  fused_k<<<3125, 256, 0, stream>>>(featsb, nbr, wt2, b2, zrow, ln_g, ln_b, out);
}